// Round 10
// baseline (666.743 us; speedup 1.0000x reference)
//
#include <hip/hip_runtime.h>
#include <math.h>

#define N_WIRES 8
#define N_LAYERS 6
#define NG 49          // grid per axis (frequencies |n|<=24 -> 49 samples exact)
#define NG2 (NG * NG)  // 2401
#define FPAD 52        // padded row length for F rows (26 x half2)
#define PRE_NBLK 1024  // 4 blocks/CU x 256 CUs: co-resident (launch_bounds(256,4))

// ws layout (bytes):
//   cnt : [0, 256)          global-barrier counter (zeroed via hipMemsetAsync)
//   E   : [256, +76832)     8 x 2401 floats (grid EVs, [i][a*49+b])
//   G   : next 76832        8 x 49 x 49 floats (intermediate DFT)
//   F   : next 40768        8 x 49 x FPAD _Float16 (2D Fourier coeffs * pi)
#define WS_E_OFF 256
#define WS_G_OFF (WS_E_OFF + 8 * NG2 * 4)
#define WS_F_OFF (WS_G_OFF + 8 * NG2 * 4)

typedef _Float16 half2v __attribute__((ext_vector_type(2)));

// ---------------------------------------------------------------------------
// Device-scope global barrier (validated on HW in round 7 — correctness held;
// r7's regression was phase-3 register spill, not the barrier). All PRE_NBLK
// blocks are co-resident: __launch_bounds__(256,4) forces VGPR<=128.
// ---------------------------------------------------------------------------
__device__ __forceinline__ void gbar(int* cnt, int target) {
    __syncthreads();
    if (threadIdx.x == 0) {
        __threadfence();
        __hip_atomic_fetch_add(cnt, 1, __ATOMIC_ACQ_REL, __HIP_MEMORY_SCOPE_AGENT);
        while (__hip_atomic_load(cnt, __ATOMIC_ACQUIRE, __HIP_MEMORY_SCOPE_AGENT) < target) {
            __builtin_amdgcn_s_sleep(2);
        }
        __threadfence();
    }
    __syncthreads();
}

// ---------------------------------------------------------------------------
// Per (layer,wire) fused-gate tables U,V with Gate = c*U + s*V
// ((c,s)=cos/sin(x0/2) even wires, (x1/2) odd wires).
// ---------------------------------------------------------------------------
__device__ __forceinline__ void compute_uv_lds(const float* __restrict__ w, float* uv, int t) {
    if (t >= N_LAYERS * N_WIRES) return;
    int i = t & 7;
    float wx = w[t * 3 + 0], wy = w[t * 3 + 1], wz = w[t * 3 + 2];
    float sx, cx, sy, cy, sz, cz;
    sincosf(0.5f * wx, &sx, &cx);
    sincosf(0.5f * wy, &sy, &cy);
    sincosf(0.5f * wz, &sz, &cz);
    float A00r = cy * cx, A00i = sy * sx;
    float A01r = -sy * cx, A01i = -cy * sx;
    float A10r = sy * cx, A10i = -cy * sx;
    float A11r = cy * cx, A11i = -sy * sx;
    float U00r = A00r * cz + A00i * sz, U00i = A00i * cz - A00r * sz;
    float U01r = A01r * cz + A01i * sz, U01i = A01i * cz - A01r * sz;
    float U10r = A10r * cz - A10i * sz, U10i = A10i * cz + A10r * sz;
    float U11r = A11r * cz - A11i * sz, U11i = A11i * cz + A11r * sz;
    float V00r, V00i, V01r, V01i, V10r, V10i, V11r, V11i;
    if ((i & 1) == 0) {
        V00r = U01i; V00i = -U01r;
        V01r = U00i; V01i = -U00r;
        V10r = U11i; V10i = -U11r;
        V11r = U10i; V11i = -U10r;
    } else {
        V00r = U01r;  V00i = U01i;
        V01r = -U00r; V01i = -U00i;
        V10r = U11r;  V10i = U11i;
        V11r = -U10r; V11i = -U10i;
    }
    float* o = uv + t * 16;
    o[0] = U00r; o[1] = U00i; o[2] = U01r; o[3] = U01i;
    o[4] = U10r; o[5] = U10i; o[6] = U11r; o[7] = U11i;
    o[8] = V00r; o[9] = V00i; o[10] = V01r; o[11] = V01i;
    o[12] = V10r; o[13] = V10i; o[14] = V11r; o[15] = V11i;
}

// ---------------------------------------------------------------------------
// One wave simulates one grid point (validated round-1/5/8 body).
// ---------------------------------------------------------------------------
__device__ void sim_point(const float* uv, int lane, int g, float* __restrict__ E) {
    const int ga = (g * 1338) >> 16;  // g/49, exact for g < 2404
    const int gb = g - ga * NG;
    const float step = (float)(2.0 * M_PI / 49.0);
    float x0 = step * (float)ga, x1 = step * (float)gb;
    float s0, c0, s1, c1;
    sincosf(0.5f * x0, &s0, &c0);
    sincosf(0.5f * x1, &s1, &c1);

    float ar[4] = {0.f, 0.f, 0.f, 0.f}, ai[4] = {0.f, 0.f, 0.f, 0.f};
    if (lane == 0) ar[0] = 1.0f;

    for (int l = 0; l < N_LAYERS; ++l) {
        const float* base = uv + l * 128;
        #pragma unroll
        for (int i = 0; i < 8; ++i) {
            const float* gm = base + i * 16;
            float ce = (i & 1) ? c1 : c0;
            float se = (i & 1) ? s1 : s0;
            float g00r = ce * gm[0] + se * gm[8],  g00i = ce * gm[1] + se * gm[9];
            float g01r = ce * gm[2] + se * gm[10], g01i = ce * gm[3] + se * gm[11];
            float g10r = ce * gm[4] + se * gm[12], g10i = ce * gm[5] + se * gm[13];
            float g11r = ce * gm[6] + se * gm[14], g11i = ce * gm[7] + se * gm[15];
            const int p = 7 - i;
            if (p >= 2) {
                const int m = 1 << (p - 2);
                const bool hi = (lane >> (p - 2)) & 1;
                float cor = hi ? g11r : g00r, coi = hi ? g11i : g00i;
                float cpr = hi ? g10r : g01r, cpi = hi ? g10i : g01i;
                #pragma unroll
                for (int j = 0; j < 4; ++j) {
                    float br = __shfl_xor(ar[j], m);
                    float bi = __shfl_xor(ai[j], m);
                    float nr = cor * ar[j] - coi * ai[j] + cpr * br - cpi * bi;
                    float ni = cor * ai[j] + coi * ar[j] + cpr * bi + cpi * br;
                    ar[j] = nr; ai[j] = ni;
                }
            } else {
                const int m = 1 << p;
                #pragma unroll
                for (int j0 = 0; j0 < 4; ++j0) {
                    if (j0 & m) continue;
                    const int j1 = j0 | m;
                    float a_r = ar[j0], a_i = ai[j0], b_r = ar[j1], b_i = ai[j1];
                    ar[j0] = g00r * a_r - g00i * a_i + g01r * b_r - g01i * b_i;
                    ai[j0] = g00r * a_i + g00i * a_r + g01r * b_i + g01i * b_r;
                    ar[j1] = g10r * a_r - g10i * a_i + g11r * b_r - g11i * b_i;
                    ai[j1] = g10r * a_i + g10i * a_r + g11r * b_i + g11i * b_r;
                }
            }
        }
        #pragma unroll
        for (int i = 0; i < 7; ++i) {
            const int pc = 7 - i, pt = 6 - i;
            if (pt >= 2) {
                const int m = 1 << (pt - 2);
                const bool ctrl = (lane >> (pc - 2)) & 1;
                #pragma unroll
                for (int j = 0; j < 4; ++j) {
                    float br = __shfl_xor(ar[j], m);
                    float bi = __shfl_xor(ai[j], m);
                    ar[j] = ctrl ? br : ar[j];
                    ai[j] = ctrl ? bi : ai[j];
                }
            } else if (pt == 1) {
                const bool ctrl = lane & 1;
                float n0r = ctrl ? ar[2] : ar[0], n0i = ctrl ? ai[2] : ai[0];
                float n2r = ctrl ? ar[0] : ar[2], n2i = ctrl ? ai[0] : ai[2];
                float n1r = ctrl ? ar[3] : ar[1], n1i = ctrl ? ai[3] : ai[1];
                float n3r = ctrl ? ar[1] : ar[3], n3i = ctrl ? ai[1] : ai[3];
                ar[0] = n0r; ai[0] = n0i; ar[1] = n1r; ai[1] = n1i;
                ar[2] = n2r; ai[2] = n2i; ar[3] = n3r; ai[3] = n3i;
            } else {
                float tr = ar[2], ti = ai[2];
                ar[2] = ar[3]; ai[2] = ai[3];
                ar[3] = tr;    ai[3] = ti;
            }
        }
    }

    float p0 = ar[0] * ar[0] + ai[0] * ai[0];
    float p1 = ar[1] * ar[1] + ai[1] * ai[1];
    float p2 = ar[2] * ar[2] + ai[2] * ai[2];
    float p3 = ar[3] * ar[3] + ai[3] * ai[3];
    float sAll = p0 + p1 + p2 + p3;

    float ev[8];
    #pragma unroll
    for (int i = 0; i < 6; ++i) ev[i] = ((lane >> (5 - i)) & 1) ? -sAll : sAll;
    ev[6] = p0 + p1 - p2 - p3;
    ev[7] = p0 - p1 + p2 - p3;

    #pragma unroll
    for (int i = 0; i < 8; ++i) {
        #pragma unroll
        for (int s = 1; s < 64; s <<= 1) ev[i] += __shfl_xor(ev[i], s);
    }

    if (lane == 0) {
        #pragma unroll
        for (int i = 0; i < 8; ++i) E[i * NG2 + g] = ev[i];
    }
}

// ---------------------------------------------------------------------------
// Fused preprocessing: phase1 grid sim -> barrier -> phase2a DFT over b ->
// barrier -> phase2b DFT over a (writes F as f16, pi folded). ONE launch
// replaces three (launch overhead was the dominant share of the non-contract
// time). Contract is a SEPARATE kernel: r7 showed fusing it perturbs regalloc
// (v1[52] spilled -> 120 MB scratch traffic).
// ---------------------------------------------------------------------------
__global__ __launch_bounds__(256, 4) void qnn_pre(const float* __restrict__ w,
                                                  int* __restrict__ cnt,
                                                  float* __restrict__ E,
                                                  float* __restrict__ G,
                                                  _Float16* __restrict__ F) {
    __shared__ float uv[N_LAYERS * N_WIRES * 16];
    compute_uv_lds(w, uv, threadIdx.x);
    __syncthreads();

    const int tid = blockIdx.x * 256 + threadIdx.x;
    const int TOT = gridDim.x * 256;
    const int lane = threadIdx.x & 63;
    const int nwaves = TOT >> 6;

    // ---- Phase 1: circuit eval on 49x49 grid (one wave per point) ----
    for (int g = tid >> 6; g < NG2; g += nwaves) sim_point(uv, lane, g, E);

    gbar(cnt, gridDim.x);

    // ---- Phase 2a: G[i][a][k] = sum_b E[i][a*49+b] * T[b][k] ----
    for (int t = tid; t < 8 * NG2; t += TOT) {
        const int i = t / NG2;
        const int r = t - i * NG2;
        const int a = (r * 1338) >> 16;
        const int k = r - a * NG;
        const float* Er = E + i * NG2 + a * NG;
        float acc = 0.f;
        if (k == 0) {
            for (int b = 0; b < NG; ++b) acc += Er[b];
            acc *= (1.0f / 49.0f);
        } else {
            int n = (k + 1) >> 1;
            float cs, ss;
            sincosf((float)(2.0 * M_PI / 49.0) * (float)n, &ss, &cs);
            float cb = 1.f, sb = 0.f;
            const bool use_cos = (k & 1);
            for (int b = 0; b < NG; ++b) {
                acc = fmaf(Er[b], use_cos ? cb : sb, acc);
                float cn = cb * cs - sb * ss;
                float sn = sb * cs + cb * ss;
                cb = cn; sb = sn;
            }
            acc *= (2.0f / 49.0f);
        }
        G[(i * NG + a) * NG + k] = acc;
    }

    gbar(cnt, 2 * gridDim.x);

    // ---- Phase 2b: F[i][kp][l] = pi * sum_a T[a][kp] * G[i][a][l] (f16) ----
    for (int t = tid; t < 8 * NG * FPAD; t += TOT) {
        const int i = t / (NG * FPAD);
        const int r = t - i * (NG * FPAD);
        const int kp = r / FPAD;
        const int l = r - kp * FPAD;
        const float PI = 3.14159265358979323846f;
        float acc = 0.f;
        if (l < NG) {
            if (kp == 0) {
                for (int a = 0; a < NG; ++a) acc += G[(i * NG + a) * NG + l];
                acc *= (PI / 49.0f);
            } else {
                int n = (kp + 1) >> 1;
                float cs, ss;
                sincosf((float)(2.0 * M_PI / 49.0) * (float)n, &ss, &cs);
                float ca = 1.f, sa = 0.f;
                const bool use_cos = (kp & 1);
                for (int a = 0; a < NG; ++a) {
                    acc = fmaf(G[(i * NG + a) * NG + l], use_cos ? ca : sa, acc);
                    float cn = ca * cs - sa * ss;
                    float sn = sa * cs + ca * ss;
                    ca = cn; sa = sn;
                }
                acc *= (2.0f * PI / 49.0f);
            }
        }
        F[(i * NG + kp) * FPAD + l] = (_Float16)acc;
    }
}

// ---------------------------------------------------------------------------
// Final contraction — byte-identical structure to round 8 (proven 64 µs,
// VGPR 40): grid (B/256,4), 2 outputs/thread, f16 v_dot2 engine, fp32 acc.
// ---------------------------------------------------------------------------
#if __has_builtin(__builtin_amdgcn_fdot2)
#define DOT2(a, b, c) __builtin_amdgcn_fdot2((a), (b), (c), false)
#else
#define DOT2(a, b, c) ((float)(a).x * (float)(b).x + (float)(a).y * (float)(b).y + (c))
#endif

__device__ __forceinline__ float dot26(const half2v* __restrict__ r, const half2v (&v)[26]) {
    float t0 = 0.f, t1 = 0.f;
    #pragma unroll
    for (int l = 0; l < 26; l += 2) {
        t0 = DOT2(r[l], v[l], t0);
        t1 = DOT2(r[l + 1], v[l + 1], t1);
    }
    return t0 + t1;
}

__global__ __launch_bounds__(256) void contract_kernel(const float* __restrict__ x,
                                                       const _Float16* __restrict__ F,
                                                       float* __restrict__ out, int B) {
    const int b = blockIdx.x * 256 + threadIdx.x;
    const int i0 = blockIdx.y * 2;
    if (b >= B) return;

    float2 xv = ((const float2*)x)[b];
    float s0, c0, s1, c1;
    sincosf(xv.x, &s0, &c0);
    sincosf(xv.y, &s1, &c1);

    float v1[FPAD];
    v1[0] = 1.0f; v1[1] = c1; v1[2] = s1;
    #pragma unroll
    for (int n = 2; n <= 24; ++n) {
        v1[2 * n - 1] = v1[2 * n - 3] * c1 - v1[2 * n - 2] * s1;
        v1[2 * n]     = v1[2 * n - 2] * c1 + v1[2 * n - 3] * s1;
    }
    v1[49] = 0.f; v1[50] = 0.f; v1[51] = 0.f;

    half2v v1h[26];
    #pragma unroll
    for (int l = 0; l < 26; ++l) {
        half2v h;
        h.x = (_Float16)v1[2 * l];
        h.y = (_Float16)v1[2 * l + 1];
        v1h[l] = h;
    }

    const half2v* base0 = (const half2v*)(F + (size_t)i0 * NG * FPAD);
    const half2v* base1 = base0 + NG * (FPAD / 2);

    float acc0 = dot26(base0, v1h);  // n=0 row
    float acc1 = dot26(base1, v1h);
    float Ck = c0, Sk = s0;
    const half2v* rp0 = base0 + (FPAD / 2);
    const half2v* rp1 = base1 + (FPAD / 2);

    #pragma unroll 2
    for (int n = 1; n <= 24; ++n) {
        float tC0 = dot26(rp0, v1h);
        float tS0 = dot26(rp0 + (FPAD / 2), v1h);
        float tC1 = dot26(rp1, v1h);
        float tS1 = dot26(rp1 + (FPAD / 2), v1h);
        acc0 = fmaf(Ck, tC0, acc0);
        acc0 = fmaf(Sk, tS0, acc0);
        acc1 = fmaf(Ck, tC1, acc1);
        acc1 = fmaf(Sk, tS1, acc1);
        float Cn = Ck * c0 - Sk * s0;
        float Sn = Sk * c0 + Ck * s0;
        Ck = Cn; Sk = Sn;
        rp0 += FPAD;  // 2 rows of 26 half2
        rp1 += FPAD;
    }

    float* o = out + (size_t)b * 8 + i0;
    o[0] = acc0;
    o[1] = acc1;
}

extern "C" void kernel_launch(void* const* d_in, const int* in_sizes, int n_in,
                              void* d_out, int out_size, void* d_ws, size_t ws_size,
                              hipStream_t stream) {
    (void)n_in; (void)out_size; (void)ws_size;
    const float* x = (const float*)d_in[0];
    const float* w = (const float*)d_in[1];
    float* out = (float*)d_out;
    char* ws = (char*)d_ws;
    int* cnt = (int*)ws;
    float* E = (float*)(ws + WS_E_OFF);
    float* G = (float*)(ws + WS_G_OFF);
    _Float16* F = (_Float16*)(ws + WS_F_OFF);
    const int B = in_sizes[0] / 2;

    (void)hipMemsetAsync(cnt, 0, 256, stream);  // ws is re-poisoned before every call
    hipLaunchKernelGGL(qnn_pre, dim3(PRE_NBLK), dim3(256), 0, stream, w, cnt, E, G, F);
    hipLaunchKernelGGL(contract_kernel, dim3((B + 255) / 256, 4), dim3(256), 0, stream,
                       x, F, out, B);
}

// Round 11
// 145.058 us; speedup vs baseline: 4.5964x; 4.5964x over previous
//
#include <hip/hip_runtime.h>
#include <math.h>

#define N_WIRES 8
#define N_LAYERS 6
#define NG 49          // grid per axis (frequencies |n|<=24 -> 49 samples exact)
#define NG2 (NG * NG)  // 2401
#define FPAD 52        // padded row length for F rows (26 x half2)

// ws layout (bytes):
//   E : [0, 76832)       8 x 2401 floats (grid EVs, [i][a*49+b])
//   F : [76832, +40768)  8 x 49 x FPAD _Float16 (2D Fourier coeffs * pi)
#define WS_E_OFF 0
#define WS_F_OFF 76832

typedef _Float16 half2v __attribute__((ext_vector_type(2)));

// ---------------------------------------------------------------------------
// Per (layer,wire) fused-gate tables U,V with Gate = c*U + s*V
// ((c,s)=cos/sin(x0/2) even wires, (x1/2) odd wires). Computed per-block in
// LDS (48 threads, trivial) to save a launch.
// ---------------------------------------------------------------------------
__device__ __forceinline__ void compute_uv_lds(const float* __restrict__ w, float* uv, int t) {
    if (t >= N_LAYERS * N_WIRES) return;
    int i = t & 7;
    float wx = w[t * 3 + 0], wy = w[t * 3 + 1], wz = w[t * 3 + 2];
    float sx, cx, sy, cy, sz, cz;
    sincosf(0.5f * wx, &sx, &cx);
    sincosf(0.5f * wy, &sy, &cy);
    sincosf(0.5f * wz, &sz, &cz);
    float A00r = cy * cx, A00i = sy * sx;
    float A01r = -sy * cx, A01i = -cy * sx;
    float A10r = sy * cx, A10i = -cy * sx;
    float A11r = cy * cx, A11i = -sy * sx;
    float U00r = A00r * cz + A00i * sz, U00i = A00i * cz - A00r * sz;
    float U01r = A01r * cz + A01i * sz, U01i = A01i * cz - A01r * sz;
    float U10r = A10r * cz - A10i * sz, U10i = A10i * cz + A10r * sz;
    float U11r = A11r * cz - A11i * sz, U11i = A11i * cz + A11r * sz;
    float V00r, V00i, V01r, V01i, V10r, V10i, V11r, V11i;
    if ((i & 1) == 0) {
        V00r = U01i; V00i = -U01r;
        V01r = U00i; V01i = -U00r;
        V10r = U11i; V10i = -U11r;
        V11r = U10i; V11i = -U10r;
    } else {
        V00r = U01r;  V00i = U01i;
        V01r = -U00r; V01i = -U00i;
        V10r = U11r;  V10i = U11i;
        V11r = -U10r; V11i = -U10i;
    }
    float* o = uv + t * 16;
    o[0] = U00r; o[1] = U00i; o[2] = U01r; o[3] = U01i;
    o[4] = U10r; o[5] = U10i; o[6] = U11r; o[7] = U11i;
    o[8] = V00r; o[9] = V00i; o[10] = V01r; o[11] = V01i;
    o[12] = V10r; o[13] = V10i; o[14] = V11r; o[15] = V11i;
}

// ---------------------------------------------------------------------------
// Grid circuit eval: one wave per grid point g=a*49+b ->
// (x0,x1)=(2*pi*a/49, 2*pi*b/49). Writes E[i][g]. (r8-proven body.)
// ---------------------------------------------------------------------------
__global__ __launch_bounds__(256) void qnn_grid_kernel(const float* __restrict__ w,
                                                       float* __restrict__ E) {
    __shared__ float uv[N_LAYERS * N_WIRES * 16];
    compute_uv_lds(w, uv, threadIdx.x);
    __syncthreads();

    const int lane = threadIdx.x & 63;
    const int g = blockIdx.x * (blockDim.x >> 6) + (threadIdx.x >> 6);
    if (g >= NG2) return;

    const int ga = (g * 1338) >> 16;  // g/49, exact for g < 2404
    const int gb = g - ga * NG;
    const float step = (float)(2.0 * M_PI / 49.0);
    float x0 = step * (float)ga, x1 = step * (float)gb;
    float s0, c0, s1, c1;
    sincosf(0.5f * x0, &s0, &c0);
    sincosf(0.5f * x1, &s1, &c1);

    float ar[4] = {0.f, 0.f, 0.f, 0.f}, ai[4] = {0.f, 0.f, 0.f, 0.f};
    if (lane == 0) ar[0] = 1.0f;

    for (int l = 0; l < N_LAYERS; ++l) {
        const float* base = uv + l * 128;
        #pragma unroll
        for (int i = 0; i < 8; ++i) {
            const float* gm = base + i * 16;
            float ce = (i & 1) ? c1 : c0;
            float se = (i & 1) ? s1 : s0;
            float g00r = ce * gm[0] + se * gm[8],  g00i = ce * gm[1] + se * gm[9];
            float g01r = ce * gm[2] + se * gm[10], g01i = ce * gm[3] + se * gm[11];
            float g10r = ce * gm[4] + se * gm[12], g10i = ce * gm[5] + se * gm[13];
            float g11r = ce * gm[6] + se * gm[14], g11i = ce * gm[7] + se * gm[15];
            const int p = 7 - i;
            if (p >= 2) {
                const int m = 1 << (p - 2);
                const bool hi = (lane >> (p - 2)) & 1;
                float cor = hi ? g11r : g00r, coi = hi ? g11i : g00i;
                float cpr = hi ? g10r : g01r, cpi = hi ? g10i : g01i;
                #pragma unroll
                for (int j = 0; j < 4; ++j) {
                    float br = __shfl_xor(ar[j], m);
                    float bi = __shfl_xor(ai[j], m);
                    float nr = cor * ar[j] - coi * ai[j] + cpr * br - cpi * bi;
                    float ni = cor * ai[j] + coi * ar[j] + cpr * bi + cpi * br;
                    ar[j] = nr; ai[j] = ni;
                }
            } else {
                const int m = 1 << p;
                #pragma unroll
                for (int j0 = 0; j0 < 4; ++j0) {
                    if (j0 & m) continue;
                    const int j1 = j0 | m;
                    float a_r = ar[j0], a_i = ai[j0], b_r = ar[j1], b_i = ai[j1];
                    ar[j0] = g00r * a_r - g00i * a_i + g01r * b_r - g01i * b_i;
                    ai[j0] = g00r * a_i + g00i * a_r + g01r * b_i + g01i * b_r;
                    ar[j1] = g10r * a_r - g10i * a_i + g11r * b_r - g11i * b_i;
                    ai[j1] = g10r * a_i + g10i * a_r + g11r * b_i + g11i * b_r;
                }
            }
        }
        #pragma unroll
        for (int i = 0; i < 7; ++i) {
            const int pc = 7 - i, pt = 6 - i;
            if (pt >= 2) {
                const int m = 1 << (pt - 2);
                const bool ctrl = (lane >> (pc - 2)) & 1;
                #pragma unroll
                for (int j = 0; j < 4; ++j) {
                    float br = __shfl_xor(ar[j], m);
                    float bi = __shfl_xor(ai[j], m);
                    ar[j] = ctrl ? br : ar[j];
                    ai[j] = ctrl ? bi : ai[j];
                }
            } else if (pt == 1) {
                const bool ctrl = lane & 1;
                float n0r = ctrl ? ar[2] : ar[0], n0i = ctrl ? ai[2] : ai[0];
                float n2r = ctrl ? ar[0] : ar[2], n2i = ctrl ? ai[0] : ai[2];
                float n1r = ctrl ? ar[3] : ar[1], n1i = ctrl ? ai[3] : ai[1];
                float n3r = ctrl ? ar[1] : ar[3], n3i = ctrl ? ai[1] : ai[3];
                ar[0] = n0r; ai[0] = n0i; ar[1] = n1r; ai[1] = n1i;
                ar[2] = n2r; ai[2] = n2i; ar[3] = n3r; ai[3] = n3i;
            } else {
                float tr = ar[2], ti = ai[2];
                ar[2] = ar[3]; ai[2] = ai[3];
                ar[3] = tr;    ai[3] = ti;
            }
        }
    }

    float p0 = ar[0] * ar[0] + ai[0] * ai[0];
    float p1 = ar[1] * ar[1] + ai[1] * ai[1];
    float p2 = ar[2] * ar[2] + ai[2] * ai[2];
    float p3 = ar[3] * ar[3] + ai[3] * ai[3];
    float sAll = p0 + p1 + p2 + p3;

    float ev[8];
    #pragma unroll
    for (int i = 0; i < 6; ++i) ev[i] = ((lane >> (5 - i)) & 1) ? -sAll : sAll;
    ev[6] = p0 + p1 - p2 - p3;
    ev[7] = p0 - p1 + p2 - p3;

    #pragma unroll
    for (int i = 0; i < 8; ++i) {
        #pragma unroll
        for (int s = 1; s < 64; s <<= 1) ev[i] += __shfl_xor(ev[i], s);
    }

    if (lane == 0) {
        #pragma unroll
        for (int i = 0; i < 8; ++i) E[i * NG2 + g] = ev[i];
    }
}

// ---------------------------------------------------------------------------
// Fused separable 2D DFT in ONE kernel (replaces dft_b + dft_a launches).
// Block (kp, i), 64 threads:
//   stage B: thread b: H[b] = f(kp) * sum_a T[a][kp] * E[i][a*49+b]  (LDS)
//   stage C: thread l: F[i][kp][l] = pi * f(l) * sum_b T[b][l] * H[b]  (f16)
// T[*][0]=1 f=1/49; T[*][2n-1]=cos f=2/49; T[*][2n]=sin f=2/49.
// Separable order swapped vs r5 (kp-side first) — mathematically identical.
// ---------------------------------------------------------------------------
__global__ __launch_bounds__(64) void dft2(const float* __restrict__ E,
                                           _Float16* __restrict__ F) {
    const int kp = blockIdx.x, i = blockIdx.y, t = threadIdx.x;
    __shared__ float Es[NG2];
    __shared__ float H[NG];
    const float step = (float)(2.0 * M_PI / 49.0);

    for (int e = t; e < NG2; e += 64) Es[e] = E[i * NG2 + e];
    __syncthreads();

    if (t < NG) {
        const int b = t;
        float acc = 0.f;
        if (kp == 0) {
            for (int a = 0; a < NG; ++a) acc += Es[a * NG + b];
            acc *= (1.0f / 49.0f);
        } else {
            const int n = (kp + 1) >> 1;
            float cs, ss;
            sincosf(step * (float)n, &ss, &cs);
            float ca = 1.f, sa = 0.f;
            const bool use_cos = (kp & 1);
            for (int a = 0; a < NG; ++a) {
                acc = fmaf(Es[a * NG + b], use_cos ? ca : sa, acc);
                float cn = ca * cs - sa * ss;
                float sn = sa * cs + ca * ss;
                ca = cn; sa = sn;
            }
            acc *= (2.0f / 49.0f);
        }
        H[b] = acc;
    }
    __syncthreads();

    if (t < FPAD) {
        const int l = t;
        const float PI = 3.14159265358979323846f;
        float acc = 0.f;
        if (l < NG) {
            if (l == 0) {
                for (int b = 0; b < NG; ++b) acc += H[b];
                acc *= (PI / 49.0f);
            } else {
                const int n = (l + 1) >> 1;
                float cs, ss;
                sincosf(step * (float)n, &ss, &cs);
                float cb = 1.f, sb = 0.f;
                const bool use_cos = (l & 1);
                for (int b = 0; b < NG; ++b) {
                    acc = fmaf(H[b], use_cos ? cb : sb, acc);
                    float cn = cb * cs - sb * ss;
                    float sn = sb * cs + cb * ss;
                    cb = cn; sb = sn;
                }
                acc *= (2.0f * PI / 49.0f);
            }
        }
        F[(i * NG + kp) * FPAD + l] = (_Float16)acc;
    }
}

// ---------------------------------------------------------------------------
// Final contraction — r8-proven structure (64 µs, VGPR 40): grid (B/256,4),
// 2 outputs/thread, f16 v_dot2 engine, fp32 acc. Only change: n-loop unroll
// 2 -> 4 to double scalar-loads in flight (VALUBusy was 63% on K$ latency).
// ---------------------------------------------------------------------------
#if __has_builtin(__builtin_amdgcn_fdot2)
#define DOT2(a, b, c) __builtin_amdgcn_fdot2((a), (b), (c), false)
#else
#define DOT2(a, b, c) ((float)(a).x * (float)(b).x + (float)(a).y * (float)(b).y + (c))
#endif

__device__ __forceinline__ float dot26(const half2v* __restrict__ r, const half2v (&v)[26]) {
    float t0 = 0.f, t1 = 0.f;
    #pragma unroll
    for (int l = 0; l < 26; l += 2) {
        t0 = DOT2(r[l], v[l], t0);
        t1 = DOT2(r[l + 1], v[l + 1], t1);
    }
    return t0 + t1;
}

__global__ __launch_bounds__(256) void contract_kernel(const float* __restrict__ x,
                                                       const _Float16* __restrict__ F,
                                                       float* __restrict__ out, int B) {
    const int b = blockIdx.x * 256 + threadIdx.x;
    const int i0 = blockIdx.y * 2;
    if (b >= B) return;

    float2 xv = ((const float2*)x)[b];
    float s0, c0, s1, c1;
    sincosf(xv.x, &s0, &c0);
    sincosf(xv.y, &s1, &c1);

    float v1[FPAD];
    v1[0] = 1.0f; v1[1] = c1; v1[2] = s1;
    #pragma unroll
    for (int n = 2; n <= 24; ++n) {
        v1[2 * n - 1] = v1[2 * n - 3] * c1 - v1[2 * n - 2] * s1;
        v1[2 * n]     = v1[2 * n - 2] * c1 + v1[2 * n - 3] * s1;
    }
    v1[49] = 0.f; v1[50] = 0.f; v1[51] = 0.f;

    half2v v1h[26];
    #pragma unroll
    for (int l = 0; l < 26; ++l) {
        half2v h;
        h.x = (_Float16)v1[2 * l];
        h.y = (_Float16)v1[2 * l + 1];
        v1h[l] = h;
    }

    const half2v* base0 = (const half2v*)(F + (size_t)i0 * NG * FPAD);
    const half2v* base1 = base0 + NG * (FPAD / 2);

    float acc0 = dot26(base0, v1h);  // n=0 row
    float acc1 = dot26(base1, v1h);
    float Ck = c0, Sk = s0;
    const half2v* rp0 = base0 + (FPAD / 2);
    const half2v* rp1 = base1 + (FPAD / 2);

    #pragma unroll 4
    for (int n = 1; n <= 24; ++n) {
        float tC0 = dot26(rp0, v1h);
        float tS0 = dot26(rp0 + (FPAD / 2), v1h);
        float tC1 = dot26(rp1, v1h);
        float tS1 = dot26(rp1 + (FPAD / 2), v1h);
        acc0 = fmaf(Ck, tC0, acc0);
        acc0 = fmaf(Sk, tS0, acc0);
        acc1 = fmaf(Ck, tC1, acc1);
        acc1 = fmaf(Sk, tS1, acc1);
        float Cn = Ck * c0 - Sk * s0;
        float Sn = Sk * c0 + Ck * s0;
        Ck = Cn; Sk = Sn;
        rp0 += FPAD;  // 2 rows of 26 half2
        rp1 += FPAD;
    }

    float* o = out + (size_t)b * 8 + i0;
    o[0] = acc0;
    o[1] = acc1;
}

extern "C" void kernel_launch(void* const* d_in, const int* in_sizes, int n_in,
                              void* d_out, int out_size, void* d_ws, size_t ws_size,
                              hipStream_t stream) {
    (void)n_in; (void)out_size; (void)ws_size;
    const float* x = (const float*)d_in[0];
    const float* w = (const float*)d_in[1];
    float* out = (float*)d_out;
    char* ws = (char*)d_ws;
    float* E = (float*)(ws + WS_E_OFF);
    _Float16* F = (_Float16*)(ws + WS_F_OFF);
    const int B = in_sizes[0] / 2;

    hipLaunchKernelGGL(qnn_grid_kernel, dim3((NG2 + 3) / 4), dim3(256), 0, stream, w, E);
    hipLaunchKernelGGL(dft2, dim3(NG, 8), dim3(64), 0, stream, E, F);
    hipLaunchKernelGGL(contract_kernel, dim3((B + 255) / 256, 4), dim3(256), 0, stream,
                       x, F, out, B);
}

// Round 12
// 139.796 us; speedup vs baseline: 4.7694x; 1.0376x over previous
//
#include <hip/hip_runtime.h>
#include <math.h>

#define N_WIRES 8
#define N_LAYERS 6
#define NG 49          // grid per axis (frequencies |n|<=24 -> 49 samples exact)
#define NG2 (NG * NG)  // 2401
#define FPAD 52        // padded row length for F rows (26 x half2)

// ws layout (bytes):
//   E : [0, 76832)       8 x 2401 floats (grid EVs, [i][a*49+b])
//   F : [76832, +40768)  8 x 49 x FPAD _Float16 (2D Fourier coeffs * pi)
#define WS_E_OFF 0
#define WS_F_OFF 76832

typedef _Float16 half2v __attribute__((ext_vector_type(2)));

// ---------------------------------------------------------------------------
// Grid circuit eval, block-per-point version: block g simulates grid point
// g=a*49+b, (x0,x1)=(2*pi*a/49, 2*pi*b/49). One amplitude per thread
// (idx = threadIdx.x, wire i at bit 7-i), exchanges via LDS.
//   - 48 post-encoding gate matrices built ONCE per block into LDS
//     (thread t<48: G = ce*U + se*V, (ce,se)=cos/sin(x0/2) even, (x1/2) odd)
//   - per-layer CNOT chain (0,1)..(6,7) composes into ONE Gray permutation:
//     src = idx ^ (idx>>1)   [CNOTs are basis permutations; prefix-XOR]
// 2401 blocks, ~3.7 KB LDS, low VGPR -> ~8 co-resident blocks/CU: the serial
// shuffle->FMA chain that throttled the wave-per-point version (2.3 waves/
// SIMD) is now latency-hidden across blocks.
// ---------------------------------------------------------------------------
__global__ __launch_bounds__(256) void qnn_grid_lds(const float* __restrict__ w,
                                                    float* __restrict__ E) {
    __shared__ float gates[N_LAYERS * N_WIRES * 8];  // {g00r,g00i,g01r,g01i,g10r,g10i,g11r,g11i}
    __shared__ float2 amps[256];
    __shared__ float partial[4][8];

    const int tid = threadIdx.x;
    const int g = blockIdx.x;
    const int ga = (g * 1338) >> 16;  // g/49, exact for g < 2404
    const int gb = g - ga * NG;
    const float step = (float)(2.0 * M_PI / 49.0);

    if (tid < N_LAYERS * N_WIRES) {
        const int i = tid & 7;
        float wx = w[tid * 3 + 0], wy = w[tid * 3 + 1], wz = w[tid * 3 + 2];
        float sx, cx, sy, cy, sz, cz;
        sincosf(0.5f * wx, &sx, &cx);
        sincosf(0.5f * wy, &sy, &cy);
        sincosf(0.5f * wz, &sz, &cz);
        float A00r = cy * cx, A00i = sy * sx;
        float A01r = -sy * cx, A01i = -cy * sx;
        float A10r = sy * cx, A10i = -cy * sx;
        float A11r = cy * cx, A11i = -sy * sx;
        float U00r = A00r * cz + A00i * sz, U00i = A00i * cz - A00r * sz;
        float U01r = A01r * cz + A01i * sz, U01i = A01i * cz - A01r * sz;
        float U10r = A10r * cz - A10i * sz, U10i = A10i * cz + A10r * sz;
        float U11r = A11r * cz - A11i * sz, U11i = A11i * cz + A11r * sz;
        float V00r, V00i, V01r, V01i, V10r, V10i, V11r, V11i;
        if ((i & 1) == 0) {
            V00r = U01i; V00i = -U01r;
            V01r = U00i; V01i = -U00r;
            V10r = U11i; V10i = -U11r;
            V11r = U10i; V11i = -U10r;
        } else {
            V00r = U01r;  V00i = U01i;
            V01r = -U00r; V01i = -U00i;
            V10r = U11r;  V10i = U11i;
            V11r = -U10r; V11i = -U10i;
        }
        // encoding: even wire -> x0 (RX), odd wire -> x1 (RY)
        const float xx = (i & 1) ? (step * (float)gb) : (step * (float)ga);
        float se, ce;
        sincosf(0.5f * xx, &se, &ce);
        float* o = gates + tid * 8;
        o[0] = ce * U00r + se * V00r;  o[1] = ce * U00i + se * V00i;
        o[2] = ce * U01r + se * V01r;  o[3] = ce * U01i + se * V01i;
        o[4] = ce * U10r + se * V10r;  o[5] = ce * U10i + se * V10i;
        o[6] = ce * U11r + se * V11r;  o[7] = ce * U11i + se * V11i;
    }

    float ar = (tid == 0) ? 1.0f : 0.0f;
    float ai = 0.0f;
    __syncthreads();

    for (int l = 0; l < N_LAYERS; ++l) {
        // 8 fused (encode ∘ RX ∘ RY ∘ RZ) gates, wire i at bit p=7-i
        #pragma unroll
        for (int i = 0; i < 8; ++i) {
            const float* gm = gates + (l * 8 + i) * 8;
            const int p = 7 - i;
            const int m = 1 << p;
            const int bit = (tid >> p) & 1;
            amps[tid] = make_float2(ar, ai);
            __syncthreads();
            float2 other = amps[tid ^ m];
            // row `bit`: slot0 amp = (bit==0)?self:other ; slot1 = (bit==0)?other:self
            float a0r = bit ? other.x : ar, a0i = bit ? other.y : ai;
            float a1r = bit ? ar : other.x, a1i = bit ? ai : other.y;
            float c0r = gm[bit * 4 + 0], c0i = gm[bit * 4 + 1];
            float c1r = gm[bit * 4 + 2], c1i = gm[bit * 4 + 3];
            float nr = c0r * a0r - c0i * a0i + c1r * a1r - c1i * a1i;
            float ni = c0r * a0i + c0i * a0r + c1r * a1i + c1i * a1r;
            __syncthreads();
            ar = nr; ai = ni;
        }
        // CNOT chain (0,1)(1,2)...(6,7) == one Gray-code permutation
        amps[tid] = make_float2(ar, ai);
        __syncthreads();
        float2 src = amps[tid ^ (tid >> 1)];
        ar = src.x; ai = src.y;
        __syncthreads();
    }

    // <Z_i> : per-thread probability, signed 64-lane butterfly, 4-wave combine
    float p = ar * ar + ai * ai;
    float ev[8];
    #pragma unroll
    for (int i = 0; i < 8; ++i) ev[i] = ((tid >> (7 - i)) & 1) ? -p : p;
    #pragma unroll
    for (int i = 0; i < 8; ++i) {
        #pragma unroll
        for (int s = 1; s < 64; s <<= 1) ev[i] += __shfl_xor(ev[i], s);
    }
    const int wave = tid >> 6, lane = tid & 63;
    if (lane == 0) {
        #pragma unroll
        for (int i = 0; i < 8; ++i) partial[wave][i] = ev[i];
    }
    __syncthreads();
    if (tid < 8) {
        E[tid * NG2 + g] = partial[0][tid] + partial[1][tid] + partial[2][tid] + partial[3][tid];
    }
}

// ---------------------------------------------------------------------------
// Fused separable 2D DFT (r11-proven). Block (kp, i), 64 threads:
//   stage B: thread b: H[b] = f(kp) * sum_a T[a][kp] * E[i][a*49+b]  (LDS)
//   stage C: thread l: F[i][kp][l] = pi * f(l) * sum_b T[b][l] * H[b]  (f16)
// ---------------------------------------------------------------------------
__global__ __launch_bounds__(64) void dft2(const float* __restrict__ E,
                                           _Float16* __restrict__ F) {
    const int kp = blockIdx.x, i = blockIdx.y, t = threadIdx.x;
    __shared__ float Es[NG2];
    __shared__ float H[NG];
    const float step = (float)(2.0 * M_PI / 49.0);

    for (int e = t; e < NG2; e += 64) Es[e] = E[i * NG2 + e];
    __syncthreads();

    if (t < NG) {
        const int b = t;
        float acc = 0.f;
        if (kp == 0) {
            for (int a = 0; a < NG; ++a) acc += Es[a * NG + b];
            acc *= (1.0f / 49.0f);
        } else {
            const int n = (kp + 1) >> 1;
            float cs, ss;
            sincosf(step * (float)n, &ss, &cs);
            float ca = 1.f, sa = 0.f;
            const bool use_cos = (kp & 1);
            for (int a = 0; a < NG; ++a) {
                acc = fmaf(Es[a * NG + b], use_cos ? ca : sa, acc);
                float cn = ca * cs - sa * ss;
                float sn = sa * cs + ca * ss;
                ca = cn; sa = sn;
            }
            acc *= (2.0f / 49.0f);
        }
        H[b] = acc;
    }
    __syncthreads();

    if (t < FPAD) {
        const int l = t;
        const float PI = 3.14159265358979323846f;
        float acc = 0.f;
        if (l < NG) {
            if (l == 0) {
                for (int b = 0; b < NG; ++b) acc += H[b];
                acc *= (PI / 49.0f);
            } else {
                const int n = (l + 1) >> 1;
                float cs, ss;
                sincosf(step * (float)n, &ss, &cs);
                float cb = 1.f, sb = 0.f;
                const bool use_cos = (l & 1);
                for (int b = 0; b < NG; ++b) {
                    acc = fmaf(H[b], use_cos ? cb : sb, acc);
                    float cn = cb * cs - sb * ss;
                    float sn = sb * cs + cb * ss;
                    cb = cn; sb = sn;
                }
                acc *= (2.0f * PI / 49.0f);
            }
        }
        F[(i * NG + kp) * FPAD + l] = (_Float16)acc;
    }
}

// ---------------------------------------------------------------------------
// Final contraction — byte-identical to r11 (59.3 µs, VGPR 36, busy 65%):
// grid (B/256,4), 2 outputs/thread, f16 v_dot2 engine, fp32 acc, unroll 4.
// ---------------------------------------------------------------------------
#if __has_builtin(__builtin_amdgcn_fdot2)
#define DOT2(a, b, c) __builtin_amdgcn_fdot2((a), (b), (c), false)
#else
#define DOT2(a, b, c) ((float)(a).x * (float)(b).x + (float)(a).y * (float)(b).y + (c))
#endif

__device__ __forceinline__ float dot26(const half2v* __restrict__ r, const half2v (&v)[26]) {
    float t0 = 0.f, t1 = 0.f;
    #pragma unroll
    for (int l = 0; l < 26; l += 2) {
        t0 = DOT2(r[l], v[l], t0);
        t1 = DOT2(r[l + 1], v[l + 1], t1);
    }
    return t0 + t1;
}

__global__ __launch_bounds__(256) void contract_kernel(const float* __restrict__ x,
                                                       const _Float16* __restrict__ F,
                                                       float* __restrict__ out, int B) {
    const int b = blockIdx.x * 256 + threadIdx.x;
    const int i0 = blockIdx.y * 2;
    if (b >= B) return;

    float2 xv = ((const float2*)x)[b];
    float s0, c0, s1, c1;
    sincosf(xv.x, &s0, &c0);
    sincosf(xv.y, &s1, &c1);

    float v1[FPAD];
    v1[0] = 1.0f; v1[1] = c1; v1[2] = s1;
    #pragma unroll
    for (int n = 2; n <= 24; ++n) {
        v1[2 * n - 1] = v1[2 * n - 3] * c1 - v1[2 * n - 2] * s1;
        v1[2 * n]     = v1[2 * n - 2] * c1 + v1[2 * n - 3] * s1;
    }
    v1[49] = 0.f; v1[50] = 0.f; v1[51] = 0.f;

    half2v v1h[26];
    #pragma unroll
    for (int l = 0; l < 26; ++l) {
        half2v h;
        h.x = (_Float16)v1[2 * l];
        h.y = (_Float16)v1[2 * l + 1];
        v1h[l] = h;
    }

    const half2v* base0 = (const half2v*)(F + (size_t)i0 * NG * FPAD);
    const half2v* base1 = base0 + NG * (FPAD / 2);

    float acc0 = dot26(base0, v1h);  // n=0 row
    float acc1 = dot26(base1, v1h);
    float Ck = c0, Sk = s0;
    const half2v* rp0 = base0 + (FPAD / 2);
    const half2v* rp1 = base1 + (FPAD / 2);

    #pragma unroll 4
    for (int n = 1; n <= 24; ++n) {
        float tC0 = dot26(rp0, v1h);
        float tS0 = dot26(rp0 + (FPAD / 2), v1h);
        float tC1 = dot26(rp1, v1h);
        float tS1 = dot26(rp1 + (FPAD / 2), v1h);
        acc0 = fmaf(Ck, tC0, acc0);
        acc0 = fmaf(Sk, tS0, acc0);
        acc1 = fmaf(Ck, tC1, acc1);
        acc1 = fmaf(Sk, tS1, acc1);
        float Cn = Ck * c0 - Sk * s0;
        float Sn = Sk * c0 + Ck * s0;
        Ck = Cn; Sk = Sn;
        rp0 += FPAD;  // 2 rows of 26 half2
        rp1 += FPAD;
    }

    float* o = out + (size_t)b * 8 + i0;
    o[0] = acc0;
    o[1] = acc1;
}

extern "C" void kernel_launch(void* const* d_in, const int* in_sizes, int n_in,
                              void* d_out, int out_size, void* d_ws, size_t ws_size,
                              hipStream_t stream) {
    (void)n_in; (void)out_size; (void)ws_size;
    const float* x = (const float*)d_in[0];
    const float* w = (const float*)d_in[1];
    float* out = (float*)d_out;
    char* ws = (char*)d_ws;
    float* E = (float*)(ws + WS_E_OFF);
    _Float16* F = (_Float16*)(ws + WS_F_OFF);
    const int B = in_sizes[0] / 2;

    hipLaunchKernelGGL(qnn_grid_lds, dim3(NG2), dim3(256), 0, stream, w, E);
    hipLaunchKernelGGL(dft2, dim3(NG, 8), dim3(64), 0, stream, E, F);
    hipLaunchKernelGGL(contract_kernel, dim3((B + 255) / 256, 4), dim3(256), 0, stream,
                       x, F, out, B);
}